// Round 4
// baseline (207.138 us; speedup 1.0000x reference)
//
#include <hip/hip_runtime.h>
#include <hip/hip_bf16.h>
#include <math.h>

#define B_DIM   4
#define N_DIM   4096
#define D_MODEL 1024
#define D_LOW   32
#define NPAIR   496          // 32*31/2
#define NROWS   (B_DIM * N_DIM)
#define KPAD3   512          // plucker K padded

typedef __bf16 bf16;
typedef __bf16 bf16x8 __attribute__((ext_vector_type(8)));
typedef __bf16 bf16x4 __attribute__((ext_vector_type(4)));
typedef float  f32x4  __attribute__((ext_vector_type(4)));

#define GLOAD_LDS16(g, l) __builtin_amdgcn_global_load_lds( \
    (__attribute__((address_space(1))) void*)(g),           \
    (__attribute__((address_space(3))) void*)(l), 16, 0, 0)

// ---------------------------------------------------------------------------
// K1: z = x @ W_red + b_red  (M=16384,K=1024,N=32) fp32 + fused x->bf16 write
// ---------------------------------------------------------------------------
__global__ __launch_bounds__(256) void k1_red(const float* __restrict__ x,
                                              const float* __restrict__ Wr,
                                              const float* __restrict__ br,
                                              float* __restrict__ z,
                                              bf16* __restrict__ xg) {
    __shared__ float xs[64][64];
    __shared__ float ws[64][32];
    const int t   = threadIdx.x;
    const int rb  = blockIdx.x * 64;
    const int col = t & 31;
    const int rg  = t >> 5;
    float acc[8];
#pragma unroll
    for (int i = 0; i < 8; ++i) acc[i] = 0.f;

    for (int k0 = 0; k0 < D_MODEL; k0 += 64) {
#pragma unroll
        for (int u = 0; u < 4; ++u) {
            int li  = t * 4 + u * 1024;
            int row = li >> 6, kk = li & 63;
            const float4 v = *reinterpret_cast<const float4*>(
                &x[(size_t)(rb + row) * D_MODEL + k0 + kk]);
            *reinterpret_cast<float4*>(&xs[row][kk]) = v;
            bf16x4 bv = { (bf16)v.x, (bf16)v.y, (bf16)v.z, (bf16)v.w };
            *reinterpret_cast<bf16x4*>(&xg[(size_t)(rb + row) * 2048 + k0 + kk]) = bv;
        }
#pragma unroll
        for (int u = 0; u < 2; ++u) {
            int li = t * 4 + u * 1024;
            int c  = li & 31, kk = li >> 5;
            const float4 v = *reinterpret_cast<const float4*>(
                &Wr[(size_t)(k0 + kk) * D_LOW + c]);
            *reinterpret_cast<float4*>(&ws[kk][c]) = v;
        }
        __syncthreads();
#pragma unroll 8
        for (int kk = 0; kk < 64; ++kk) {
            float w = ws[kk][col];
#pragma unroll
            for (int rr = 0; rr < 8; ++rr) acc[rr] += xs[rg * 8 + rr][kk] * w;
        }
        __syncthreads();
    }
    const float bias = br[col];
#pragma unroll
    for (int rr = 0; rr < 8; ++rr)
        z[(size_t)(rb + rg * 8 + rr) * D_LOW + col] = acc[rr] + bias;
}

// ---------------------------------------------------------------------------
// K2: plucker_avg -> bf16 [row][512].  One wave per row, no barriers.
// ---------------------------------------------------------------------------
__global__ __launch_bounds__(256) void k2_plucker(const float* __restrict__ z,
                                                  bf16* __restrict__ plb) {
    const int wv   = threadIdx.x >> 6;
    const int lane = threadIdx.x & 63;
    const int row  = blockIdx.x * 4 + wv;
    const int t    = row & (N_DIM - 1);
    const int c    = lane & 31;

    float zc = z[(size_t)row * D_LOW + c];
    float zp[4];
    float red[9];
    red[0] = zc * zc;
#pragma unroll
    for (int li = 0; li < 4; ++li) {
        const int lag = 1 << li;
        zp[li] = (t >= lag) ? z[(size_t)(row - lag) * D_LOW + c] : 0.f;
        red[1 + li] = zc * zp[li];
        red[5 + li] = zp[li] * zp[li];
    }
#pragma unroll
    for (int m = 1; m < 32; m <<= 1) {
#pragma unroll
        for (int i = 0; i < 9; ++i) red[i] += __shfl_xor(red[i], m);
    }
    float cnt = 0.f;
#pragma unroll
    for (int li = 0; li < 4; ++li) cnt += (t >= (1 << li)) ? 1.f : 0.f;
    const float inv = 1.f / fmaxf(cnt, 1.f);

    float w = 0.f;
#pragma unroll
    for (int li = 0; li < 4; ++li) {
        float n2 = fmaxf(red[0] * red[5 + li] - red[1 + li] * red[1 + li], 0.f);
        float nr = sqrtf(n2);
        float s  = (t >= (1 << li)) ? inv / fmaxf(nr, 1e-6f) : 0.f;
        w += s * zp[li];
    }

#pragma unroll
    for (int u = 0; u < 8; ++u) {
        const int k = u * 64 + lane;
        float v = 0.f;
        if (k < NPAIR) {
            int kk = k, i = 0;
            while (kk >= 31 - i) { kk -= 31 - i; ++i; }
            const int j = i + 1 + kk;
            float zci = __shfl(zc, i), zcj = __shfl(zc, j);
            float wi  = __shfl(w, i),  wj  = __shfl(w, j);
            v = zci * wj - zcj * wi;
        }
        plb[(size_t)row * KPAD3 + k] = (bf16)v;
    }
}

// ---------------------------------------------------------------------------
// transpose+convert: dst[n][k] = (k < Ksrc) ? src[k][n] : 0
// ---------------------------------------------------------------------------
__global__ __launch_bounds__(256) void transpose_cvt(const float* __restrict__ src,
                                                     bf16* __restrict__ dst,
                                                     int Ksrc, int Kpad) {
    __shared__ float tile[32][36];
    const int t  = threadIdx.x;
    const int kb = blockIdx.x * 32;
    const int nb = blockIdx.y * 32;
    int li = t * 4;
    int kl = li >> 5, nl = li & 31;
    float4 v = {0.f, 0.f, 0.f, 0.f};
    if (kb + kl < Ksrc)
        v = *reinterpret_cast<const float4*>(&src[(size_t)(kb + kl) * 1024 + nb + nl]);
    tile[kl][nl + 0] = v.x; tile[kl][nl + 1] = v.y;
    tile[kl][nl + 2] = v.z; tile[kl][nl + 3] = v.w;
    __syncthreads();
    int nl2 = li >> 5, kl2 = li & 31;
    bf16x4 o = { (bf16)tile[kl2 + 0][nl2], (bf16)tile[kl2 + 1][nl2],
                 (bf16)tile[kl2 + 2][nl2], (bf16)tile[kl2 + 3][nl2] };
    *reinterpret_cast<bf16x4*>(&dst[(size_t)(nb + nl2) * Kpad + kb + kl2]) = o;
}

// ---------------------------------------------------------------------------
// 256x256 MFMA GEMM, BK=64, 8 waves (2Mx4N).
// LDS: A triple-buffered (3x32KB) + B double-buffered (2x32KB) = 160KB.
// Stage issue at tile TOP: B one tile ahead, A two tiles ahead; counted
// vmcnt(12) (tail: 8/0).  XOR-swizzled LDS; XCD-bijective block swizzle.
// Requires NT = KDIM/64 >= 4.
// ---------------------------------------------------------------------------
template <int KDIM, bool GATE>
__global__ __launch_bounds__(512, 2) void gemm8(const bf16* __restrict__ A,
                                                const bf16* __restrict__ Bt,
                                                const float* __restrict__ bias,
                                                const float* __restrict__ x,
                                                bf16* __restrict__ xg,
                                                float* __restrict__ out) {
    extern __shared__ char lds[];            // 163840 B
    const int t    = threadIdx.x;
    const int w    = t >> 6, lane = t & 63;
    const int wr   = w >> 2, wc = w & 3;     // 2 x 4 wave grid
    const int l15  = lane & 15, lhi = lane >> 4;

    // XCD-bijective swizzle: 256 blocks, 8 XCDs; 32 blocks/XCD share one B panel
    const int fid = blockIdx.x;
    const int swz = (fid & 7) * 32 + (fid >> 3);
    const int nb  = (swz >> 6) * 256;        // 4 N panels
    const int mb  = (swz & 63) * 256;        // 64 M panels

    // staging: thread covers 16B; row = t>>3, colblk = (t&7)^(row&7)
    const int srow = t >> 3;
    const int scol = ((t & 7) ^ (srow & 7)) * 8;
    const size_t aRow = (size_t)(mb + srow) * KDIM + scol;
    const size_t bRow = (size_t)(nb + srow) * KDIM + scol;
    const int sdst = t * 16;
    char* const ldsA = lds;                  // 3 slots x 32KB
    char* const ldsB = lds + 98304;          // 2 slots x 32KB

#define STAGE_A(d, h, kb) do { \
    GLOAD_LDS16(A + aRow + (size_t)((h) * 128) * KDIM + (kb),      ldsA + (d) * 32768 + (h) * 16384 + sdst); \
    GLOAD_LDS16(A + aRow + (size_t)((h) * 128 + 64) * KDIM + (kb), ldsA + (d) * 32768 + (h) * 16384 + 8192 + sdst); } while (0)
#define STAGE_B(d, h, kb) do { \
    GLOAD_LDS16(Bt + bRow + (size_t)((h) * 128) * KDIM + (kb),      ldsB + (d) * 32768 + (h) * 16384 + sdst); \
    GLOAD_LDS16(Bt + bRow + (size_t)((h) * 128 + 64) * KDIM + (kb), ldsB + (d) * 32768 + (h) * 16384 + 8192 + sdst); } while (0)

    f32x4 acc[8][4];
#pragma unroll
    for (int i = 0; i < 8; ++i)
#pragma unroll
        for (int j = 0; j < 4; ++j) acc[i][j] = (f32x4){0.f, 0.f, 0.f, 0.f};

    // prologue: B(0)->Bslot0, A(0)->Aslot0, A(1)->Aslot1  (12 loads)
    STAGE_B(0, 0, 0); STAGE_B(0, 1, 0);
    STAGE_A(0, 0, 0); STAGE_A(0, 1, 0);
    STAGE_A(1, 0, 64); STAGE_A(1, 1, 64);

    const int NT = KDIM / 64;
    int ar = 0, br = 0, aw = 2;
    bf16x8 afr[4][2], bfr[4][2];
    const int swx = (l15 & 7) << 4;          // read-side XOR

    for (int kt = 0; kt < NT; ++kt) {
        // ---- top-of-tile stage issue: B(kt+1), A(kt+2)
        if (kt + 1 < NT) { const int kb1 = (kt + 1) * 64;
                           STAGE_B(br ^ 1, 0, kb1); STAGE_B(br ^ 1, 1, kb1); }
        if (kt + 2 < NT) { const int kb2 = (kt + 2) * 64;
                           STAGE_A(aw, 0, kb2); STAGE_A(aw, 1, kb2); }
        // counted drain: exactly {A(kt), B(kt)} retired
        if (kt < NT - 2)       asm volatile("s_waitcnt vmcnt(12)" ::: "memory");
        else if (kt == NT - 2) asm volatile("s_waitcnt vmcnt(8)"  ::: "memory");
        else                   asm volatile("s_waitcnt vmcnt(0)"  ::: "memory");
        asm volatile("s_barrier" ::: "memory");

        const char* Ab = ldsA + ar * 32768 + wr * 16384;
        const char* Bb = ldsB + br * 32768 + (wc >> 1) * 16384;

        // ---- read B all + A mq=0
#pragma unroll
        for (int nf = 0; nf < 4; ++nf)
#pragma unroll
            for (int ks = 0; ks < 2; ++ks) {
                int lin = (wc & 1) * 8192 + nf * 2048 + l15 * 128 + ks * 64 + lhi * 16;
                bfr[nf][ks] = *reinterpret_cast<const bf16x8*>(Bb + (lin ^ swx));
            }
#pragma unroll
        for (int mf = 0; mf < 4; ++mf)
#pragma unroll
            for (int ks = 0; ks < 2; ++ks) {
                int lin = mf * 2048 + l15 * 128 + ks * 64 + lhi * 16;
                afr[mf][ks] = *reinterpret_cast<const bf16x8*>(Ab + (lin ^ swx));
            }
        __builtin_amdgcn_s_setprio(1);
#pragma unroll
        for (int mf = 0; mf < 4; ++mf)
#pragma unroll
            for (int nf = 0; nf < 4; ++nf)
#pragma unroll
                for (int ks = 0; ks < 2; ++ks)
                    acc[mf][nf] = __builtin_amdgcn_mfma_f32_16x16x32_bf16(
                        afr[mf][ks], bfr[nf][ks], acc[mf][nf], 0, 0, 0);
        __builtin_amdgcn_s_setprio(0);

        // ---- read A mq=1, second half of MFMAs
#pragma unroll
        for (int mf = 0; mf < 4; ++mf)
#pragma unroll
            for (int ks = 0; ks < 2; ++ks) {
                int lin = 8192 + mf * 2048 + l15 * 128 + ks * 64 + lhi * 16;
                afr[mf][ks] = *reinterpret_cast<const bf16x8*>(Ab + (lin ^ swx));
            }
        __builtin_amdgcn_s_setprio(1);
#pragma unroll
        for (int mf = 0; mf < 4; ++mf)
#pragma unroll
            for (int nf = 0; nf < 4; ++nf)
#pragma unroll
                for (int ks = 0; ks < 2; ++ks)
                    acc[4 + mf][nf] = __builtin_amdgcn_mfma_f32_16x16x32_bf16(
                        afr[mf][ks], bfr[nf][ks], acc[4 + mf][nf], 0, 0, 0);
        __builtin_amdgcn_s_setprio(0);

        asm volatile("s_barrier" ::: "memory");   // readers done before reuse
        ar = (ar == 2) ? 0 : ar + 1;
        aw = (aw == 2) ? 0 : aw + 1;
        br ^= 1;
    }
#undef STAGE_A
#undef STAGE_B

    // epilogue
#pragma unroll
    for (int mi = 0; mi < 8; ++mi) {
#pragma unroll
        for (int nf = 0; nf < 4; ++nf) {
            const int col = nb + wc * 64 + nf * 16 + l15;
            const float bv = bias[col];
#pragma unroll
            for (int r = 0; r < 4; ++r) {
                const int row = mb + wr * 128 + mi * 16 + lhi * 4 + r;
                float v = acc[mi][nf][r] + bv;
                if constexpr (GATE) {
                    float gate = 1.f / (1.f + expf(-v));
                    float xv = x[(size_t)row * D_MODEL + col];
                    float gv = (float)xg[(size_t)row * 2048 + 1024 + col];
                    out[(size_t)row * D_MODEL + col] = gate * xv + (1.f - gate) * gv;
                } else {
                    xg[(size_t)row * 2048 + 1024 + col] = (bf16)v;
                }
            }
        }
    }
}

// ---------------------------------------------------------------------------
extern "C" void kernel_launch(void* const* d_in, const int* in_sizes, int n_in,
                              void* d_out, int out_size, void* d_ws, size_t ws_size,
                              hipStream_t stream) {
    const float* x  = (const float*)d_in[0];
    const float* Wr = (const float*)d_in[1];
    const float* br = (const float*)d_in[2];
    const float* We = (const float*)d_in[3];
    const float* be = (const float*)d_in[4];
    const float* Wg = (const float*)d_in[5];
    const float* bg = (const float*)d_in[6];
    float* out = (float*)d_out;

    char* ws = (char*)d_ws;
    float* z   = (float*)(ws);                          //  2 MB
    bf16* plb  = (bf16*)(ws + (2u << 20));              // 16 MB  [16384][512]
    bf16* xg   = (bf16*)(ws + (18u << 20));             // 64 MB  [16384][2048]
    bf16* WeT  = (bf16*)(ws + (82u << 20));             //  1 MB  [1024][512]
    bf16* WgT  = (bf16*)(ws + (83u << 20));             //  4 MB  [1024][2048]

    // allow 160KB dynamic LDS
    (void)hipFuncSetAttribute(reinterpret_cast<const void*>(&gemm8<KPAD3, false>),
                              hipFuncAttributeMaxDynamicSharedMemorySize, 163840);
    (void)hipFuncSetAttribute(reinterpret_cast<const void*>(&gemm8<2048, true>),
                              hipFuncAttributeMaxDynamicSharedMemorySize, 163840);

    k1_red<<<NROWS / 64, 256, 0, stream>>>(x, Wr, br, z, xg);
    transpose_cvt<<<dim3(KPAD3 / 32, 1024 / 32), 256, 0, stream>>>(We, WeT, NPAIR, KPAD3);
    transpose_cvt<<<dim3(2048 / 32, 1024 / 32), 256, 0, stream>>>(Wg, WgT, 2048, 2048);
    k2_plucker<<<NROWS / 4, 256, 0, stream>>>(z, plb);

    gemm8<KPAD3, false><<<256, 512, 163840, stream>>>(plb, WeT, be, nullptr, xg, nullptr);
    gemm8<2048, true><<<256, 512, 163840, stream>>>(xg, WgT, bg, x, xg, out);
}

// Round 5
// 198.169 us; speedup vs baseline: 1.0453x; 1.0453x over previous
//
#include <hip/hip_runtime.h>
#include <hip/hip_bf16.h>
#include <math.h>

#define B_DIM   4
#define N_DIM   4096
#define D_MODEL 1024
#define D_LOW   32
#define NPAIR   496          // 32*31/2
#define NROWS   (B_DIM * N_DIM)
#define KPAD3   512          // plucker K padded

typedef __bf16 bf16;
typedef __bf16 bf16x8 __attribute__((ext_vector_type(8)));
typedef __bf16 bf16x4 __attribute__((ext_vector_type(4)));
typedef float  f32x4  __attribute__((ext_vector_type(4)));

#define GLOAD_LDS16(g, l) __builtin_amdgcn_global_load_lds( \
    (__attribute__((address_space(1))) void*)(g),           \
    (__attribute__((address_space(3))) void*)(l), 16, 0, 0)

// ---------------------------------------------------------------------------
// K1: z = x @ W_red + b_red  (M=16384,K=1024,N=32) fp32 + fused x->bf16 write
// ---------------------------------------------------------------------------
__global__ __launch_bounds__(256) void k1_red(const float* __restrict__ x,
                                              const float* __restrict__ Wr,
                                              const float* __restrict__ br,
                                              float* __restrict__ z,
                                              bf16* __restrict__ xg) {
    __shared__ float xs[64][64];
    __shared__ float ws[64][32];
    const int t   = threadIdx.x;
    const int rb  = blockIdx.x * 64;
    const int col = t & 31;
    const int rg  = t >> 5;
    float acc[8];
#pragma unroll
    for (int i = 0; i < 8; ++i) acc[i] = 0.f;

    for (int k0 = 0; k0 < D_MODEL; k0 += 64) {
#pragma unroll
        for (int u = 0; u < 4; ++u) {
            int li  = t * 4 + u * 1024;
            int row = li >> 6, kk = li & 63;
            const float4 v = *reinterpret_cast<const float4*>(
                &x[(size_t)(rb + row) * D_MODEL + k0 + kk]);
            *reinterpret_cast<float4*>(&xs[row][kk]) = v;
            bf16x4 bv = { (bf16)v.x, (bf16)v.y, (bf16)v.z, (bf16)v.w };
            *reinterpret_cast<bf16x4*>(&xg[(size_t)(rb + row) * 2048 + k0 + kk]) = bv;
        }
#pragma unroll
        for (int u = 0; u < 2; ++u) {
            int li = t * 4 + u * 1024;
            int c  = li & 31, kk = li >> 5;
            const float4 v = *reinterpret_cast<const float4*>(
                &Wr[(size_t)(k0 + kk) * D_LOW + c]);
            *reinterpret_cast<float4*>(&ws[kk][c]) = v;
        }
        __syncthreads();
#pragma unroll 8
        for (int kk = 0; kk < 64; ++kk) {
            float w = ws[kk][col];
#pragma unroll
            for (int rr = 0; rr < 8; ++rr) acc[rr] += xs[rg * 8 + rr][kk] * w;
        }
        __syncthreads();
    }
    const float bias = br[col];
#pragma unroll
    for (int rr = 0; rr < 8; ++rr)
        z[(size_t)(rb + rg * 8 + rr) * D_LOW + col] = acc[rr] + bias;
}

// ---------------------------------------------------------------------------
// K2: plucker_avg -> bf16 [row][512].  One wave per row, no barriers.
// ---------------------------------------------------------------------------
__global__ __launch_bounds__(256) void k2_plucker(const float* __restrict__ z,
                                                  bf16* __restrict__ plb) {
    const int wv   = threadIdx.x >> 6;
    const int lane = threadIdx.x & 63;
    const int row  = blockIdx.x * 4 + wv;
    const int t    = row & (N_DIM - 1);
    const int c    = lane & 31;

    float zc = z[(size_t)row * D_LOW + c];
    float zp[4];
    float red[9];
    red[0] = zc * zc;
#pragma unroll
    for (int li = 0; li < 4; ++li) {
        const int lag = 1 << li;
        zp[li] = (t >= lag) ? z[(size_t)(row - lag) * D_LOW + c] : 0.f;
        red[1 + li] = zc * zp[li];
        red[5 + li] = zp[li] * zp[li];
    }
#pragma unroll
    for (int m = 1; m < 32; m <<= 1) {
#pragma unroll
        for (int i = 0; i < 9; ++i) red[i] += __shfl_xor(red[i], m);
    }
    float cnt = 0.f;
#pragma unroll
    for (int li = 0; li < 4; ++li) cnt += (t >= (1 << li)) ? 1.f : 0.f;
    const float inv = 1.f / fmaxf(cnt, 1.f);

    float w = 0.f;
#pragma unroll
    for (int li = 0; li < 4; ++li) {
        float n2 = fmaxf(red[0] * red[5 + li] - red[1 + li] * red[1 + li], 0.f);
        float nr = sqrtf(n2);
        float s  = (t >= (1 << li)) ? inv / fmaxf(nr, 1e-6f) : 0.f;
        w += s * zp[li];
    }

#pragma unroll
    for (int u = 0; u < 8; ++u) {
        const int k = u * 64 + lane;
        float v = 0.f;
        if (k < NPAIR) {
            int kk = k, i = 0;
            while (kk >= 31 - i) { kk -= 31 - i; ++i; }
            const int j = i + 1 + kk;
            float zci = __shfl(zc, i), zcj = __shfl(zc, j);
            float wi  = __shfl(w, i),  wj  = __shfl(w, j);
            v = zci * wj - zcj * wi;
        }
        plb[(size_t)row * KPAD3 + k] = (bf16)v;
    }
}

// ---------------------------------------------------------------------------
// transpose+convert: dst[n][k] = (k < Ksrc) ? src[k][n] : 0
// ---------------------------------------------------------------------------
__global__ __launch_bounds__(256) void transpose_cvt(const float* __restrict__ src,
                                                     bf16* __restrict__ dst,
                                                     int Ksrc, int Kpad) {
    __shared__ float tile[32][36];
    const int t  = threadIdx.x;
    const int kb = blockIdx.x * 32;
    const int nb = blockIdx.y * 32;
    int li = t * 4;
    int kl = li >> 5, nl = li & 31;
    float4 v = {0.f, 0.f, 0.f, 0.f};
    if (kb + kl < Ksrc)
        v = *reinterpret_cast<const float4*>(&src[(size_t)(kb + kl) * 1024 + nb + nl]);
    tile[kl][nl + 0] = v.x; tile[kl][nl + 1] = v.y;
    tile[kl][nl + 2] = v.z; tile[kl][nl + 3] = v.w;
    __syncthreads();
    int nl2 = li >> 5, kl2 = li & 31;
    bf16x4 o = { (bf16)tile[kl2 + 0][nl2], (bf16)tile[kl2 + 1][nl2],
                 (bf16)tile[kl2 + 2][nl2], (bf16)tile[kl2 + 3][nl2] };
    *reinterpret_cast<bf16x4*>(&dst[(size_t)(nb + nl2) * Kpad + kb + kl2]) = o;
}

// ---------------------------------------------------------------------------
// 256x256 MFMA GEMM, BK=64, 8 waves (2Mx4N), 128KB dbuf LDS.
// m201-style 8-phase schedule over 2 K-tiles/iter:
//   quadrant order per K-tile: (m0n0),(m1n0),(m1n1),(m0n1)
//   per phase: {stage 1 half-tile | 4-12 ds_read | bar | setprio+16 MFMA | bar}
//   counted vmcnt(2) at phases 4 & 8 only (verified drain schedule).
// A [M][KDIM] bf16; Bt [1024][KDIM] bf16.  Requires NT = KDIM/64 even, >= 2.
// ---------------------------------------------------------------------------
template <int KDIM, bool GATE>
__global__ __launch_bounds__(512, 2) void gemm8p(const bf16* __restrict__ A,
                                                 const bf16* __restrict__ Bt,
                                                 const float* __restrict__ bias,
                                                 bf16* __restrict__ xg,
                                                 float* __restrict__ out) {
    extern __shared__ char lds[];            // 131072: A 2x32KB | B 2x32KB
    const int t    = threadIdx.x;
    const int w    = t >> 6, lane = t & 63;
    const int wr   = w >> 2, wc = w & 3;     // 2 x 4 wave grid
    const int l15  = lane & 15, lhi = lane >> 4;

    // XCD-bijective swizzle: 256 blocks, 8 XCDs; 32 blocks/XCD share one B panel
    const int fid = blockIdx.x;
    const int swz = (fid & 7) * 32 + (fid >> 3);
    const int nb  = (swz >> 6) * 256;
    const int mb  = (swz & 63) * 256;

    const int srow = t >> 3;                 // 0..63
    const int scol = ((t & 7) ^ (srow & 7)) * 8;
    const size_t aOff = (size_t)(mb + srow) * KDIM + scol;
    const size_t bOff = (size_t)(nb + srow) * KDIM + scol;
    char* const ldsA = lds;                  // + d*32768 + h*16384
    char* const ldsB = lds + 65536;

#define STAGE_A(d, h, kb) do { \
    GLOAD_LDS16(A + aOff + (size_t)((h) * 128) * KDIM + (kb),      ldsA + (d) * 32768 + (h) * 16384 + t * 16); \
    GLOAD_LDS16(A + aOff + (size_t)((h) * 128 + 64) * KDIM + (kb), ldsA + (d) * 32768 + (h) * 16384 + 8192 + t * 16); } while (0)
#define STAGE_B(d, h, kb) do { \
    GLOAD_LDS16(Bt + bOff + (size_t)((h) * 128) * KDIM + (kb),      ldsB + (d) * 32768 + (h) * 16384 + t * 16); \
    GLOAD_LDS16(Bt + bOff + (size_t)((h) * 128 + 64) * KDIM + (kb), ldsB + (d) * 32768 + (h) * 16384 + 8192 + t * 16); } while (0)

    const int swx = (l15 & 7) << 4;
#define LDA(d, mq_) do { const char* Ab_ = ldsA + (d) * 32768 + wr * 16384; \
    _Pragma("unroll") for (int mf = 0; mf < 4; ++mf) \
    _Pragma("unroll") for (int ks = 0; ks < 2; ++ks) { \
        int lin = ((mq_) * 64 + mf * 16 + l15) * 128 + ks * 64 + lhi * 16; \
        afr[mf][ks] = *reinterpret_cast<const bf16x8*>(Ab_ + (lin ^ swx)); } } while (0)
#define LDB(d, nq_) do { const char* Bb_ = ldsB + (d) * 32768 + (wc >> 1) * 16384; \
    _Pragma("unroll") for (int nf = 0; nf < 2; ++nf) \
    _Pragma("unroll") for (int ks = 0; ks < 2; ++ks) { \
        int lin = ((wc & 1) * 64 + (nq_) * 32 + nf * 16 + l15) * 128 + ks * 64 + lhi * 16; \
        bfr[nf][ks] = *reinterpret_cast<const bf16x8*>(Bb_ + (lin ^ swx)); } } while (0)
#define MMA(mq_, nq_) do { __builtin_amdgcn_s_setprio(1); \
    _Pragma("unroll") for (int mf = 0; mf < 4; ++mf) \
    _Pragma("unroll") for (int nf = 0; nf < 2; ++nf) \
    _Pragma("unroll") for (int ks = 0; ks < 2; ++ks) \
        acc[(mq_) * 4 + mf][(nq_) * 2 + nf] = __builtin_amdgcn_mfma_f32_16x16x32_bf16( \
            afr[mf][ks], bfr[nf][ks], acc[(mq_) * 4 + mf][(nq_) * 2 + nf], 0, 0, 0); \
    __builtin_amdgcn_s_setprio(0); } while (0)
#define BAR() asm volatile("s_barrier" ::: "memory")

    f32x4 acc[8][4];
#pragma unroll
    for (int i = 0; i < 8; ++i)
#pragma unroll
        for (int j = 0; j < 4; ++j) acc[i][j] = (f32x4){0.f, 0.f, 0.f, 0.f};
    bf16x8 afr[4][2], bfr[2][2];

    // prologue: tile0 (buf0, 4 half-tiles) + tile1's B h0 (buf1)
    STAGE_B(0, 0, 0); STAGE_B(0, 1, 0);
    STAGE_A(0, 0, 0); STAGE_A(0, 1, 0);
    STAGE_B(1, 0, 64);
    asm volatile("s_waitcnt vmcnt(2)" ::: "memory");
    BAR();

    const int NT    = KDIM / 64;
    const int ITERS = NT / 2;
    for (int it = 0; it < ITERS; ++it) {
        const int k1e = (it * 2 + 1) * 64;
        const int k2e = (it * 2 + 2) * 64;
        const int k3e = (it * 2 + 3) * 64;
        const bool s2 = (it * 2 + 2) < NT;
        const bool s3 = (it * 2 + 3) < NT;
        const bool lastit = (it == ITERS - 1);

        // ---- P1: tile 2t, quadrant (0,0)
        STAGE_B(1, 1, k1e);
        LDA(0, 0); LDB(0, 0);
        BAR(); MMA(0, 0); BAR();
        // ---- P2: quadrant (1,0)
        STAGE_A(1, 0, k1e);
        LDA(0, 1);
        BAR(); MMA(1, 0); BAR();
        // ---- P3: quadrant (1,1)
        STAGE_A(1, 1, k1e);
        LDB(0, 1);
        BAR(); MMA(1, 1); BAR();
        // ---- P4: quadrant (0,1); drain so tile 2t+1 is resident
        if (s2) STAGE_B(0, 0, k2e);
        LDA(0, 0);
        BAR(); MMA(0, 1);
        if (lastit) asm volatile("s_waitcnt vmcnt(0)" ::: "memory");
        else        asm volatile("s_waitcnt vmcnt(2)" ::: "memory");
        BAR();

        // ---- P5: tile 2t+1, quadrant (0,0)
        if (s2) STAGE_B(0, 1, k2e);
        LDA(1, 0); LDB(1, 0);
        BAR(); MMA(0, 0); BAR();
        // ---- P6: quadrant (1,0)
        if (s2) STAGE_A(0, 0, k2e);
        LDA(1, 1);
        BAR(); MMA(1, 0); BAR();
        // ---- P7: quadrant (1,1)
        if (s2) STAGE_A(0, 1, k2e);
        LDB(1, 1);
        BAR(); MMA(1, 1); BAR();
        // ---- P8: quadrant (0,1); drain so tile 2t+2 is resident
        if (s3) STAGE_B(1, 0, k3e);
        LDA(1, 0);
        BAR(); MMA(0, 1);
        if (lastit) asm volatile("s_waitcnt vmcnt(0)" ::: "memory");
        else        asm volatile("s_waitcnt vmcnt(2)" ::: "memory");
        BAR();
    }
#undef STAGE_A
#undef STAGE_B
#undef LDA
#undef LDB
#undef MMA
#undef BAR

    // epilogue
#pragma unroll
    for (int mi = 0; mi < 8; ++mi) {
#pragma unroll
        for (int nf = 0; nf < 4; ++nf) {
            const int col = nb + wc * 64 + nf * 16 + l15;
            const float bv = bias[col];
#pragma unroll
            for (int r = 0; r < 4; ++r) {
                const int row = mb + wr * 128 + mi * 16 + lhi * 4 + r;
                float v = acc[mi][nf][r] + bv;
                if constexpr (GATE) {
                    float gate = 1.f / (1.f + expf(-v));
                    float xv = (float)xg[(size_t)row * 2048 + col];
                    float gv = (float)xg[(size_t)row * 2048 + 1024 + col];
                    out[(size_t)row * D_MODEL + col] = gate * xv + (1.f - gate) * gv;
                } else {
                    xg[(size_t)row * 2048 + 1024 + col] = (bf16)v;
                }
            }
        }
    }
}

// ---------------------------------------------------------------------------
extern "C" void kernel_launch(void* const* d_in, const int* in_sizes, int n_in,
                              void* d_out, int out_size, void* d_ws, size_t ws_size,
                              hipStream_t stream) {
    const float* x  = (const float*)d_in[0];
    const float* Wr = (const float*)d_in[1];
    const float* br = (const float*)d_in[2];
    const float* We = (const float*)d_in[3];
    const float* be = (const float*)d_in[4];
    const float* Wg = (const float*)d_in[5];
    const float* bg = (const float*)d_in[6];
    float* out = (float*)d_out;

    char* ws = (char*)d_ws;
    float* z   = (float*)(ws);                          //  2 MB
    bf16* plb  = (bf16*)(ws + (2u << 20));              // 16 MB  [16384][512]
    bf16* xg   = (bf16*)(ws + (18u << 20));             // 64 MB  [16384][2048]
    bf16* WeT  = (bf16*)(ws + (82u << 20));             //  1 MB  [1024][512]
    bf16* WgT  = (bf16*)(ws + (83u << 20));             //  4 MB  [1024][2048]

    (void)hipFuncSetAttribute(reinterpret_cast<const void*>(&gemm8p<KPAD3, false>),
                              hipFuncAttributeMaxDynamicSharedMemorySize, 131072);
    (void)hipFuncSetAttribute(reinterpret_cast<const void*>(&gemm8p<2048, true>),
                              hipFuncAttributeMaxDynamicSharedMemorySize, 131072);

    k1_red<<<NROWS / 64, 256, 0, stream>>>(x, Wr, br, z, xg);
    transpose_cvt<<<dim3(KPAD3 / 32, 1024 / 32), 256, 0, stream>>>(We, WeT, NPAIR, KPAD3);
    transpose_cvt<<<dim3(2048 / 32, 1024 / 32), 256, 0, stream>>>(Wg, WgT, 2048, 2048);
    k2_plucker<<<NROWS / 4, 256, 0, stream>>>(z, plb);

    gemm8p<KPAD3, false><<<256, 512, 131072, stream>>>(plb, WeT, be, xg, nullptr);
    gemm8p<2048, true><<<256, 512, 131072, stream>>>(xg, WgT, bg, xg, out);
}